// Round 16
// baseline (242.214 us; speedup 1.0000x reference)
//
#include <hip/hip_runtime.h>
#include <math.h>

#define NN 6000
#define EE 100000
#define ELL (EE + NN)   // edges + self loops for GAT
#define CAP 64          // bucket-CSR capacity per node (max deg ~45 << 64)

// packed CSR entry: src (13b) | rel<<13 | self<<14
#define PK_SRC(p)  ((p) & 0x1FFF)
#define PK_REL(p)  (((p) >> 13) & 1)
#define PK_SELF(p) ((p) & 0x4000)

typedef __attribute__((ext_vector_type(8))) short frag8;           // 8 bf16 (4 VGPR)
typedef __attribute__((ext_vector_type(4))) float f32x4;
typedef __attribute__((ext_vector_type(8))) unsigned short u16x8;  // 16B of bf16

__device__ __forceinline__ unsigned short f2bf(float f){
  unsigned u = __float_as_uint(f);
  unsigned r = u + 0x7FFFu + ((u >> 16) & 1u);   // round-to-nearest-even
  return (unsigned short)(r >> 16);
}
__device__ __forceinline__ float bf2f(unsigned short s){
  return __uint_as_float(((unsigned)s) << 16);
}

// ---- fused: bucket-CSR fill + weight prep (W0 bf16) + w1->Bt bf16 ----
// cursor[] doubles as the per-node degree after this kernel completes.
__global__ void k_pdc(const int* __restrict__ ei, const int* __restrict__ et,
                      int* __restrict__ cursor, int* __restrict__ pks,
                      const float* __restrict__ basis0, const float* __restrict__ comp0,
                      const float* __restrict__ b1,const float* __restrict__ c1,const float* __restrict__ r1,
                      const float* __restrict__ b2,const float* __restrict__ c2,const float* __restrict__ r2,
                      const float* __restrict__ b3,const float* __restrict__ c3,const float* __restrict__ r3,
                      const float* __restrict__ w1,
                      unsigned short* __restrict__ W016, float* __restrict__ Wcat,
                      unsigned short* __restrict__ Bt16){
  int t0 = blockIdx.x*256 + threadIdx.x;
  if (t0 < ELL){
    int d, pk;
    if (t0 < EE){
      d = ei[EE+t0];
      pk = ei[t0] | (et[t0] << 13);
    } else {
      d = t0 - EE; pk = d | 0x4000;
    }
    int pos = atomicAdd(&cursor[d], 1);
    pks[d*CAP + pos] = pk;
  }
  if (t0 < 2*NN*32){
    int r = t0 / (NN*32);
    int no = t0 - r*(NN*32);
    float acc = 0.f;
    #pragma unroll
    for (int b=0;b<4;b++) acc += comp0[r*4+b] * basis0[b*(NN*32)+no];
    W016[t0] = f2bf(acc);
    return;
  }
  int tw = t0 - 2*NN*32;
  if (tw < 24576){
    const float *bb,*cc,*rr; int I,O; int t = tw;
    if (tw < 6144)        { bb=b1;cc=c1;rr=r1;I=32;O=64; }
    else if (tw < 18432)  { bb=b2;cc=c2;rr=r2;I=64;O=64; t -= 6144; }
    else                  { bb=b3;cc=c3;rr=r3;I=64;O=32; t -= 18432; }
    int C = 3*O;
    int i = t / C; int col = t - i*C;
    float v;
    if (col < O) v = rr[i*O + col];
    else {
      int r = (col - O) / O; int o = col - O - r*O;
      v = 0.f;
      #pragma unroll
      for (int b=0;b<4;b++) v += cc[r*4+b]*bb[(b*I+i)*O + o];
    }
    Wcat[tw] = v;
    return;
  }
  int tb = tw - 24576;           // Bt16: [n][k], n in [0,256), k in [0,512)
  if (tb >= 256*512) return;
  int n = tb >> 9, k = tb & 511;
  float v = (n < 128) ? w1[k*128 + n] : w1[(512+k)*128 + (n-128)];
  Bt16[tb] = f2bf(v);
}

// ---- F1: layer-0 gather (x=I) + layer-1 nodemm -> H16 [N,192] ----
// per-relation counts derived locally while walking the bucket.
__global__ void __launch_bounds__(256) k_f1(
    const unsigned short* __restrict__ W016, const float* __restrict__ root,
    const float* __restrict__ rbias0,
    const int* __restrict__ degc, const int* __restrict__ pks,
    const float* __restrict__ Wc, unsigned short* __restrict__ Hout){
  __shared__ float sx[8*32];
  int n0 = blockIdx.x*8;
  int t = threadIdx.x, nl = t>>5, o = t&31, n = n0+nl;
  int r0 = n*CAP, r1 = r0 + degc[n];
  float a0 = 0.f, a1 = 0.f, c0 = 0.f, c1 = 0.f;
  for (int j=r0;j<r1;j++){
    int p = pks[j];
    if (PK_SELF(p)) continue;
    float v = bf2f(W016[(PK_REL(p)*NN + PK_SRC(p))*32 + o]);
    if (PK_REL(p)==0){ a0 += v; c0 += 1.f; } else { a1 += v; c1 += 1.f; }
  }
  sx[nl*32+o] = tanhf(root[n*32+o] + rbias0[o]
                      + a0/fmaxf(c0,1.f) + a1/fmaxf(c1,1.f));
  __syncthreads();
  if (t < 192){
    float acc[8] = {0,0,0,0,0,0,0,0};
    for (int i=0;i<32;i++){
      float w = Wc[i*192 + t];
      #pragma unroll
      for (int tt=0;tt<8;tt++) acc[tt] += sx[tt*32+i]*w;
    }
    #pragma unroll
    for (int tt=0;tt<8;tt++) Hout[(n0+tt)*192 + t] = f2bf(acc[tt]);
  }
}

// ---- F2: ragg<64> (Hin stride 192) + nodemm 64x192 -> Hout [N,192] ----
__global__ void __launch_bounds__(256) k_f2(
    const unsigned short* __restrict__ Hin, const float* __restrict__ rbias,
    const int* __restrict__ degc, const int* __restrict__ pks,
    const float* __restrict__ Wc, unsigned short* __restrict__ Hout){
  __shared__ float sx[8*64];
  int n0 = blockIdx.x*8;
  int t = threadIdx.x, nl = t>>5, o0 = (t&31)*2, n = n0+nl;
  int r0 = n*CAP, r1 = r0 + degc[n];
  float a00=0.f, a01=0.f, a10=0.f, a11=0.f, c0=0.f, c1=0.f;
  for (int j=r0;j<r1;j++){
    int p = pks[j];
    if (PK_SELF(p)) continue;
    int rel = PK_REL(p);
    unsigned hv = *(const unsigned*)&Hin[PK_SRC(p)*192 + 64 + rel*64 + o0];
    float v0 = bf2f((unsigned short)(hv & 0xFFFF));
    float v1 = bf2f((unsigned short)(hv >> 16));
    if (rel==0){ a00 += v0; a01 += v1; c0 += 1.f; } else { a10 += v0; a11 += v1; c1 += 1.f; }
  }
  float i0 = 1.f/fmaxf(c0,1.f), i1 = 1.f/fmaxf(c1,1.f);
  sx[nl*64+o0]   = tanhf(bf2f(Hin[n*192+o0])   + rbias[o0]   + a00*i0 + a10*i1);
  sx[nl*64+o0+1] = tanhf(bf2f(Hin[n*192+o0+1]) + rbias[o0+1] + a01*i0 + a11*i1);
  __syncthreads();
  if (t < 192){
    float acc[8] = {0,0,0,0,0,0,0,0};
    for (int i=0;i<64;i++){
      float w = Wc[i*192 + t];
      #pragma unroll
      for (int tt=0;tt<8;tt++) acc[tt] += sx[tt*64+i]*w;
    }
    #pragma unroll
    for (int tt=0;tt<8;tt++) Hout[(n0+tt)*192 + t] = f2bf(acc[tt]);
  }
}

// ---- F3: ragg<64> (Hin stride 192) + nodemm 64x96 -> Hout [N,96] ----
__global__ void __launch_bounds__(256) k_f3(
    const unsigned short* __restrict__ Hin, const float* __restrict__ rbias,
    const int* __restrict__ degc, const int* __restrict__ pks,
    const float* __restrict__ Wc, unsigned short* __restrict__ Hout){
  __shared__ float sx[8*64];
  int n0 = blockIdx.x*8;
  int t = threadIdx.x, nl = t>>5, o0 = (t&31)*2, n = n0+nl;
  int r0 = n*CAP, r1 = r0 + degc[n];
  float a00=0.f, a01=0.f, a10=0.f, a11=0.f, c0=0.f, c1=0.f;
  for (int j=r0;j<r1;j++){
    int p = pks[j];
    if (PK_SELF(p)) continue;
    int rel = PK_REL(p);
    unsigned hv = *(const unsigned*)&Hin[PK_SRC(p)*192 + 64 + rel*64 + o0];
    float v0 = bf2f((unsigned short)(hv & 0xFFFF));
    float v1 = bf2f((unsigned short)(hv >> 16));
    if (rel==0){ a00 += v0; a01 += v1; c0 += 1.f; } else { a10 += v0; a11 += v1; c1 += 1.f; }
  }
  float i0 = 1.f/fmaxf(c0,1.f), i1 = 1.f/fmaxf(c1,1.f);
  sx[nl*64+o0]   = tanhf(bf2f(Hin[n*192+o0])   + rbias[o0]   + a00*i0 + a10*i1);
  sx[nl*64+o0+1] = tanhf(bf2f(Hin[n*192+o0+1]) + rbias[o0+1] + a01*i0 + a11*i1);
  __syncthreads();
  if (t < 192){
    int c = t % 96, grp = t / 96;            // grp 0/1: nodes grp*4..+3
    float acc[4] = {0,0,0,0};
    for (int i=0;i<64;i++){
      float w = Wc[i*96 + c];
      #pragma unroll
      for (int tt=0;tt<4;tt++) acc[tt] += sx[(grp*4+tt)*64+i]*w;
    }
    #pragma unroll
    for (int tt=0;tt<4;tt++) Hout[(n0+grp*4+tt)*96 + c] = f2bf(acc[tt]);
  }
}

// ---- F4: ragg<32> (Hin stride 96) + GAT h=x@gw + scores ----
__global__ void __launch_bounds__(256) k_f4(
    const unsigned short* __restrict__ Hin, const float* __restrict__ rbias,
    const int* __restrict__ degc, const int* __restrict__ pks,
    const float* __restrict__ gw, const float* __restrict__ as_,
    const float* __restrict__ ad_,
    unsigned short* __restrict__ h16, float* __restrict__ asv, float* __restrict__ adv){
  __shared__ float sx[8*32];
  __shared__ float red[4][16];
  int n0 = blockIdx.x*8;
  int t = threadIdx.x, nl = t>>5, o = t&31, n = n0+nl;
  int r0 = n*CAP, r1 = r0 + degc[n];
  float a0=0.f, a1=0.f, c0=0.f, c1=0.f;
  for (int j=r0;j<r1;j++){
    int p = pks[j];
    if (PK_SELF(p)) continue;
    int rel = PK_REL(p);
    float v = bf2f(Hin[PK_SRC(p)*96 + 32 + rel*32 + o]);
    if (rel==0){ a0 += v; c0 += 1.f; } else { a1 += v; c1 += 1.f; }
  }
  sx[nl*32+o] = tanhf(bf2f(Hin[n*96+o]) + rbias[o]
                      + a0/fmaxf(c0,1.f) + a1/fmaxf(c1,1.f));
  __syncthreads();
  int c2 = t*2;
  float2 acc[8];
  #pragma unroll
  for (int k=0;k<8;k++) acc[k] = {0.f,0.f};
  for (int i=0;i<32;i++){
    const float2 g = *(const float2*)&gw[i*512 + c2];
    #pragma unroll
    for (int k=0;k<8;k++){
      float xv = sx[k*32+i];
      acc[k].x += xv*g.x; acc[k].y += xv*g.y;
    }
  }
  const float2 a2 = *(const float2*)&as_[c2];
  const float2 d2 = *(const float2*)&ad_[c2];
  float sa[8], sd[8];
  #pragma unroll
  for (int k=0;k<8;k++){
    ushort2 ov;
    ov.x = f2bf(acc[k].x); ov.y = f2bf(acc[k].y);
    *(ushort2*)&h16[(n0+k)*512 + c2] = ov;
    sa[k] = acc[k].x*a2.x + acc[k].y*a2.y;
    sd[k] = acc[k].x*d2.x + acc[k].y*d2.y;
  }
  #pragma unroll
  for (int m=32;m>0;m>>=1){
    #pragma unroll
    for (int k=0;k<8;k++){ sa[k] += __shfl_xor(sa[k],m,64); sd[k] += __shfl_xor(sd[k],m,64); }
  }
  int wv = t>>6;
  if ((t&63)==0){
    #pragma unroll
    for (int k=0;k<8;k++){ red[wv][k]=sa[k]; red[wv][8+k]=sd[k]; }
  }
  __syncthreads();
  if (t<8)        asv[n0+t]   = red[0][t]+red[1][t]+red[2][t]+red[3][t];
  else if (t<16)  adv[n0+t-8] = red[0][t]+red[1][t]+red[2][t]+red[3][t];
}

// ---- k_gab: fused GAT softmax-aggregate + MFMA edge-MLP GEMM (v2) ----
// 750 blocks x 256 thr (4 waves), 8-node tiles. Wave w: phase A = 2 nodes via
// shfl-broadcast; result rows in padded LDS (SGS=520 -> 2-way bank alias max).
// Phase B: wave w = cols w*64..+63; A rows 8..15 alias rows 0..7 (outputs unused).
#define SGS 520
__global__ void __launch_bounds__(256) k_gab(
    const int* __restrict__ degc, const int* __restrict__ pks,
    const float* __restrict__ asv, const float* __restrict__ adv,
    const unsigned short* __restrict__ h16, const float* __restrict__ bias,
    const unsigned short* __restrict__ Bt16, unsigned short* __restrict__ P16){
  __shared__ unsigned short sg[8*SGS];   // 8.1 KB
  int t = threadIdx.x;
  int wv = t >> 6, lane = t & 63;
  int n0 = blockIdx.x*8;
  const float4 b0 = *(const float4*)&bias[lane*8];
  const float4 b1v = *(const float4*)&bias[lane*8+4];
  for (int i=0;i<2;i++){
    int n = n0 + wv*2 + i;
    int r0 = n*CAP, r1 = r0 + degc[n];
    float advn = adv[n];
    float m = -1e30f;
    for (int j = r0 + lane; j < r1; j += 64){
      float a = asv[PK_SRC(pks[j])] + advn; a = (a>=0.f)? a : 0.2f*a;
      m = fmaxf(m, a);
    }
    #pragma unroll
    for (int off=32;off>0;off>>=1) m = fmaxf(m, __shfl_xor(m,off,64));
    float acc[8] = {0,0,0,0,0,0,0,0};
    float sumex = 0.f;
    for (int base = r0; base < r1; base += 64){
      int j = base + lane;
      float ex = 0.f; int src = 0;
      if (j < r1){
        int p = pks[j]; src = PK_SRC(p);
        float a = asv[src] + advn; a = (a>=0.f)? a : 0.2f*a;
        ex = expf(a - m);
        sumex += ex;
      }
      int ce = min(64, r1 - base);
      for (int e = 0; e < ce; e++){
        float cf = __shfl(ex, e, 64);
        int s    = __shfl(src, e, 64);
        const u16x8 hv = *(const u16x8*)&h16[(size_t)s*512 + lane*8];
        #pragma unroll
        for (int q=0;q<8;q++) acc[q] += cf * bf2f(hv[q]);
      }
    }
    #pragma unroll
    for (int off=32;off>0;off>>=1) sumex += __shfl_xor(sumex,off,64);
    float inv = 1.f / fmaxf(sumex, 1e-16f);
    u16x8 o;
    o[0] = f2bf(fmaxf(acc[0]*inv + b0.x, 0.f));
    o[1] = f2bf(fmaxf(acc[1]*inv + b0.y, 0.f));
    o[2] = f2bf(fmaxf(acc[2]*inv + b0.z, 0.f));
    o[3] = f2bf(fmaxf(acc[3]*inv + b0.w, 0.f));
    o[4] = f2bf(fmaxf(acc[4]*inv + b1v.x, 0.f));
    o[5] = f2bf(fmaxf(acc[5]*inv + b1v.y, 0.f));
    o[6] = f2bf(fmaxf(acc[6]*inv + b1v.z, 0.f));
    o[7] = f2bf(fmaxf(acc[7]*inv + b1v.w, 0.f));
    *(u16x8*)&sg[(wv*2+i)*SGS + lane*8] = o;
  }
  __syncthreads();
  // phase B: wave wv computes rows 0..7 x cols wv*64..wv*64+63
  int kq = (lane >> 4)*8, mrow = lane & 15;
  const unsigned short* bb16 = Bt16 + (size_t)(wv*64 + mrow)*512 + kq;
  const unsigned short* arow = sg + (mrow & 7)*SGS + kq;   // rows 8..15 alias 0..7
  f32x4 acc0 = {0,0,0,0}, acc1 = {0,0,0,0}, acc2 = {0,0,0,0}, acc3 = {0,0,0,0};
  for (int k = 0; k < 512; k += 32){
    frag8 a = *(const frag8*)(arow + k);
    frag8 bg0 = *(const frag8*)(bb16 + k);
    frag8 bg1 = *(const frag8*)(bb16 + 16*512 + k);
    frag8 bg2 = *(const frag8*)(bb16 + 32*512 + k);
    frag8 bg3 = *(const frag8*)(bb16 + 48*512 + k);
    acc0 = __builtin_amdgcn_mfma_f32_16x16x32_bf16(a, bg0, acc0, 0, 0, 0);
    acc1 = __builtin_amdgcn_mfma_f32_16x16x32_bf16(a, bg1, acc1, 0, 0, 0);
    acc2 = __builtin_amdgcn_mfma_f32_16x16x32_bf16(a, bg2, acc2, 0, 0, 0);
    acc3 = __builtin_amdgcn_mfma_f32_16x16x32_bf16(a, bg3, acc3, 0, 0, 0);
  }
  if ((lane >> 4) < 2){                 // C/D rows = quad*4+i; rows 0..7 valid
    int rowb = n0 + (lane >> 4)*4;
    int col  = wv*64 + mrow;
    #pragma unroll
    for (int i=0;i<4;i++){
      P16[(size_t)(rowb+i)*256 + col     ] = f2bf(acc0[i]);
      P16[(size_t)(rowb+i)*256 + col + 16] = f2bf(acc1[i]);
      P16[(size_t)(rowb+i)*256 + col + 32] = f2bf(acc2[i]);
      P16[(size_t)(rowb+i)*256 + col + 48] = f2bf(acc3[i]);
    }
  }
}

// per-edge MLP head: 16 lanes/edge, bf16 P loads
__global__ void k_edge(const int* __restrict__ ei, const unsigned short* __restrict__ P16,
                       const float* __restrict__ b1,
                       const float* __restrict__ w2, const float* __restrict__ b2,
                       float* __restrict__ out){
  int e = blockIdx.x*16 + (threadIdx.x >> 4);
  int l = threadIdx.x & 15;            // lane covers channels [l*8, l*8+8)
  if (e >= EE) return;
  int s = ei[e], d = ei[EE+e];
  const u16x8 Av = *(const u16x8*)&P16[(size_t)s*256 + l*8];
  const u16x8 Bv = *(const u16x8*)&P16[(size_t)d*256 + 128 + l*8];
  const float4 b1a = *(const float4*)&b1[l*8];
  const float4 b1b = *(const float4*)&b1[l*8+4];
  const float4 w2a = *(const float4*)&w2[l*8];
  const float4 w2b = *(const float4*)&w2[l*8+4];
  float h0 = fmaxf(bf2f(Av[0])+bf2f(Bv[0])+b1a.x, 0.f);
  float h1 = fmaxf(bf2f(Av[1])+bf2f(Bv[1])+b1a.y, 0.f);
  float h2 = fmaxf(bf2f(Av[2])+bf2f(Bv[2])+b1a.z, 0.f);
  float h3 = fmaxf(bf2f(Av[3])+bf2f(Bv[3])+b1a.w, 0.f);
  float h4 = fmaxf(bf2f(Av[4])+bf2f(Bv[4])+b1b.x, 0.f);
  float h5 = fmaxf(bf2f(Av[5])+bf2f(Bv[5])+b1b.y, 0.f);
  float h6 = fmaxf(bf2f(Av[6])+bf2f(Bv[6])+b1b.z, 0.f);
  float h7 = fmaxf(bf2f(Av[7])+bf2f(Bv[7])+b1b.w, 0.f);
  float acc = h0*w2a.x + h1*w2a.y + h2*w2a.z + h3*w2a.w
            + h4*w2b.x + h5*w2b.y + h6*w2b.z + h7*w2b.w;
  #pragma unroll
  for (int m=8;m>0;m>>=1) acc += __shfl_xor(acc,m,64);
  if (l==0) out[e] = 1.f/(1.f + expf(-(acc + b2[0])));
}

extern "C" void kernel_launch(void* const* d_in, const int* in_sizes, int n_in,
                              void* d_out, int out_size, void* d_ws, size_t ws_size,
                              hipStream_t stream){
  const float* basis0 = (const float*)d_in[0];
  const float* comp0  = (const float*)d_in[1];
  const float* root0  = (const float*)d_in[2];
  const float* rbias0 = (const float*)d_in[3];
  const float* basis1 = (const float*)d_in[4];
  const float* comp1  = (const float*)d_in[5];
  const float* root1  = (const float*)d_in[6];
  const float* rbias1 = (const float*)d_in[7];
  const float* basis2 = (const float*)d_in[8];
  const float* comp2  = (const float*)d_in[9];
  const float* root2  = (const float*)d_in[10];
  const float* rbias2 = (const float*)d_in[11];
  const float* basis3 = (const float*)d_in[12];
  const float* comp3  = (const float*)d_in[13];
  const float* root3  = (const float*)d_in[14];
  const float* rbias3 = (const float*)d_in[15];
  const float* gat_w = (const float*)d_in[16];
  const float* a_src = (const float*)d_in[17];
  const float* a_dst = (const float*)d_in[18];
  const float* gat_b = (const float*)d_in[19];
  const float* w1 = (const float*)d_in[20];
  const float* b1 = (const float*)d_in[21];
  const float* w2 = (const float*)d_in[22];
  const float* b2 = (const float*)d_in[23];
  const int* ei = (const int*)d_in[24];
  const int* et = (const int*)d_in[25];
  float* out = (float*)d_out;

  // workspace carve-up (16B-aligned sections)
  float* p = (float*)d_ws;
  int* cursor = (int*)p; p += NN;              // doubles as degree after k_pdc
  int* pks    = (int*)p; p += NN*CAP;          // bucket CSR (64 slots/node)
  unsigned short* W016 = (unsigned short*)p; p += NN*32;       // 2*NN*32 bf16
  float* Wcat = p; p += 24576;
  unsigned short* Bt16 = (unsigned short*)p; p += 256*512/2;
  unsigned short* H16a = (unsigned short*)p; p += NN*96;       // NN*192 bf16
  unsigned short* H16b = (unsigned short*)p; p += NN*96;       // NN*192 bf16
  unsigned short* h16  = (unsigned short*)p; p += NN*256;      // NN*512 bf16
  float* asv  = p; p += NN;
  float* adv  = p; p += NN;
  unsigned short* P16 = (unsigned short*)p; p += NN*128;       // NN*256 bf16

  auto grid = [](long long n){ return dim3((unsigned)((n + 255)/256)); };

  // ---- zero cursor only, then single fused prep kernel ----
  hipMemsetAsync(cursor, 0, (size_t)NN*sizeof(int), stream);
  k_pdc<<<grid(2LL*NN*32 + 24576 + 256*512),256,0,stream>>>(ei, et, cursor, pks,
        basis0, comp0, basis1,comp1,root1, basis2,comp2,root2,
        basis3,comp3,root3, w1, W016, Wcat, Bt16);

  // ---- RGCN stack (fused gather+mm per layer; rel-counts derived locally) ----
  k_f1<<<dim3(NN/8),256,0,stream>>>(W016, root0, rbias0, cursor, pks, Wcat, H16a);
  k_f2<<<dim3(NN/8),256,0,stream>>>(H16a, rbias1, cursor, pks, Wcat + 6144, H16b);
  k_f3<<<dim3(NN/8),256,0,stream>>>(H16b, rbias2, cursor, pks, Wcat + 18432, H16a);
  k_f4<<<dim3(NN/8),256,0,stream>>>(H16a, rbias3, cursor, pks,
                                    gat_w, a_src, a_dst, h16, asv, adv);

  // ---- GAT softmax+aggregate fused with edge-MLP MFMA GEMM ----
  k_gab<<<dim3(NN/8),256,0,stream>>>(cursor, pks, asv, adv, h16, gat_b, Bt16, P16);

  // ---- edge head ----
  k_edge<<<dim3((EE+15)/16),256,0,stream>>>(ei, P16, b1, w2, b2, out);
}

// Round 17
// 232.353 us; speedup vs baseline: 1.0424x; 1.0424x over previous
//
#include <hip/hip_runtime.h>
#include <math.h>

#define NN 6000
#define EE 100000
#define ELL (EE + NN)   // edges + self loops for GAT
#define CAP 64          // bucket-CSR capacity per node (max deg ~45 << 64)

// packed CSR entry: src (13b) | rel<<13 | self<<14
#define PK_SRC(p)  ((p) & 0x1FFF)
#define PK_REL(p)  (((p) >> 13) & 1)
#define PK_SELF(p) ((p) & 0x4000)

typedef __attribute__((ext_vector_type(8))) short frag8;           // 8 bf16 (4 VGPR)
typedef __attribute__((ext_vector_type(4))) float f32x4;
typedef __attribute__((ext_vector_type(8))) unsigned short u16x8;  // 16B of bf16

__device__ __forceinline__ unsigned short f2bf(float f){
  unsigned u = __float_as_uint(f);
  unsigned r = u + 0x7FFFu + ((u >> 16) & 1u);   // round-to-nearest-even
  return (unsigned short)(r >> 16);
}
__device__ __forceinline__ float bf2f(unsigned short s){
  return __uint_as_float(((unsigned)s) << 16);
}

// ---- fused: bucket-CSR fill + weight prep (W0 bf16) + w1->Bt bf16 ----
// cursor[] doubles as the per-node degree after this kernel completes.
__global__ void k_pdc(const int* __restrict__ ei, const int* __restrict__ et,
                      int* __restrict__ cursor, int* __restrict__ pks,
                      const float* __restrict__ basis0, const float* __restrict__ comp0,
                      const float* __restrict__ b1,const float* __restrict__ c1,const float* __restrict__ r1,
                      const float* __restrict__ b2,const float* __restrict__ c2,const float* __restrict__ r2,
                      const float* __restrict__ b3,const float* __restrict__ c3,const float* __restrict__ r3,
                      const float* __restrict__ w1,
                      unsigned short* __restrict__ W016, float* __restrict__ Wcat,
                      unsigned short* __restrict__ Bt16){
  int t0 = blockIdx.x*256 + threadIdx.x;
  if (t0 < ELL){
    int d, pk;
    if (t0 < EE){
      d = ei[EE+t0];
      pk = ei[t0] | (et[t0] << 13);
    } else {
      d = t0 - EE; pk = d | 0x4000;
    }
    int pos = atomicAdd(&cursor[d], 1);
    pks[d*CAP + pos] = pk;
  }
  if (t0 < 2*NN*32){
    int r = t0 / (NN*32);
    int no = t0 - r*(NN*32);
    float acc = 0.f;
    #pragma unroll
    for (int b=0;b<4;b++) acc += comp0[r*4+b] * basis0[b*(NN*32)+no];
    W016[t0] = f2bf(acc);
    return;
  }
  int tw = t0 - 2*NN*32;
  if (tw < 24576){
    const float *bb,*cc,*rr; int I,O; int t = tw;
    if (tw < 6144)        { bb=b1;cc=c1;rr=r1;I=32;O=64; }
    else if (tw < 18432)  { bb=b2;cc=c2;rr=r2;I=64;O=64; t -= 6144; }
    else                  { bb=b3;cc=c3;rr=r3;I=64;O=32; t -= 18432; }
    int C = 3*O;
    int i = t / C; int col = t - i*C;
    float v;
    if (col < O) v = rr[i*O + col];
    else {
      int r = (col - O) / O; int o = col - O - r*O;
      v = 0.f;
      #pragma unroll
      for (int b=0;b<4;b++) v += cc[r*4+b]*bb[(b*I+i)*O + o];
    }
    Wcat[tw] = v;
    return;
  }
  int tb = tw - 24576;           // Bt16: [n][k], n in [0,256), k in [0,512)
  if (tb >= 256*512) return;
  int n = tb >> 9, k = tb & 511;
  float v = (n < 128) ? w1[k*128 + n] : w1[(512+k)*128 + (n-128)];
  Bt16[tb] = f2bf(v);
}

// ---- F1: layer-0 gather (x=I) + layer-1 nodemm -> H16 [N,192] ----
__global__ void __launch_bounds__(256) k_f1(
    const unsigned short* __restrict__ W016, const float* __restrict__ root,
    const float* __restrict__ rbias0,
    const int* __restrict__ degc, const int* __restrict__ pks,
    const float* __restrict__ Wc, unsigned short* __restrict__ Hout){
  __shared__ float sx[8*32];
  int n0 = blockIdx.x*8;
  int t = threadIdx.x, nl = t>>5, o = t&31, n = n0+nl;
  int r0 = n*CAP, r1 = r0 + degc[n];
  float a0 = 0.f, a1 = 0.f, c0 = 0.f, c1 = 0.f;
  for (int j=r0;j<r1;j++){
    int p = pks[j];
    if (PK_SELF(p)) continue;
    float v = bf2f(W016[(PK_REL(p)*NN + PK_SRC(p))*32 + o]);
    if (PK_REL(p)==0){ a0 += v; c0 += 1.f; } else { a1 += v; c1 += 1.f; }
  }
  sx[nl*32+o] = tanhf(root[n*32+o] + rbias0[o]
                      + a0/fmaxf(c0,1.f) + a1/fmaxf(c1,1.f));
  __syncthreads();
  if (t < 192){
    float acc[8] = {0,0,0,0,0,0,0,0};
    for (int i=0;i<32;i++){
      float w = Wc[i*192 + t];
      #pragma unroll
      for (int tt=0;tt<8;tt++) acc[tt] += sx[tt*32+i]*w;
    }
    #pragma unroll
    for (int tt=0;tt<8;tt++) Hout[(n0+tt)*192 + t] = f2bf(acc[tt]);
  }
}

// ---- F2: ragg<64> (Hin stride 192) + nodemm 64x192 -> Hout [N,192] ----
__global__ void __launch_bounds__(256) k_f2(
    const unsigned short* __restrict__ Hin, const float* __restrict__ rbias,
    const int* __restrict__ degc, const int* __restrict__ pks,
    const float* __restrict__ Wc, unsigned short* __restrict__ Hout){
  __shared__ float sx[8*64];
  int n0 = blockIdx.x*8;
  int t = threadIdx.x, nl = t>>5, o0 = (t&31)*2, n = n0+nl;
  int r0 = n*CAP, r1 = r0 + degc[n];
  float a00=0.f, a01=0.f, a10=0.f, a11=0.f, c0=0.f, c1=0.f;
  for (int j=r0;j<r1;j++){
    int p = pks[j];
    if (PK_SELF(p)) continue;
    int rel = PK_REL(p);
    unsigned hv = *(const unsigned*)&Hin[PK_SRC(p)*192 + 64 + rel*64 + o0];
    float v0 = bf2f((unsigned short)(hv & 0xFFFF));
    float v1 = bf2f((unsigned short)(hv >> 16));
    if (rel==0){ a00 += v0; a01 += v1; c0 += 1.f; } else { a10 += v0; a11 += v1; c1 += 1.f; }
  }
  float i0 = 1.f/fmaxf(c0,1.f), i1 = 1.f/fmaxf(c1,1.f);
  sx[nl*64+o0]   = tanhf(bf2f(Hin[n*192+o0])   + rbias[o0]   + a00*i0 + a10*i1);
  sx[nl*64+o0+1] = tanhf(bf2f(Hin[n*192+o0+1]) + rbias[o0+1] + a01*i0 + a11*i1);
  __syncthreads();
  if (t < 192){
    float acc[8] = {0,0,0,0,0,0,0,0};
    for (int i=0;i<64;i++){
      float w = Wc[i*192 + t];
      #pragma unroll
      for (int tt=0;tt<8;tt++) acc[tt] += sx[tt*64+i]*w;
    }
    #pragma unroll
    for (int tt=0;tt<8;tt++) Hout[(n0+tt)*192 + t] = f2bf(acc[tt]);
  }
}

// ---- F3: ragg<64> (Hin stride 192) + nodemm 64x96 -> Hout [N,96] ----
__global__ void __launch_bounds__(256) k_f3(
    const unsigned short* __restrict__ Hin, const float* __restrict__ rbias,
    const int* __restrict__ degc, const int* __restrict__ pks,
    const float* __restrict__ Wc, unsigned short* __restrict__ Hout){
  __shared__ float sx[8*64];
  int n0 = blockIdx.x*8;
  int t = threadIdx.x, nl = t>>5, o0 = (t&31)*2, n = n0+nl;
  int r0 = n*CAP, r1 = r0 + degc[n];
  float a00=0.f, a01=0.f, a10=0.f, a11=0.f, c0=0.f, c1=0.f;
  for (int j=r0;j<r1;j++){
    int p = pks[j];
    if (PK_SELF(p)) continue;
    int rel = PK_REL(p);
    unsigned hv = *(const unsigned*)&Hin[PK_SRC(p)*192 + 64 + rel*64 + o0];
    float v0 = bf2f((unsigned short)(hv & 0xFFFF));
    float v1 = bf2f((unsigned short)(hv >> 16));
    if (rel==0){ a00 += v0; a01 += v1; c0 += 1.f; } else { a10 += v0; a11 += v1; c1 += 1.f; }
  }
  float i0 = 1.f/fmaxf(c0,1.f), i1 = 1.f/fmaxf(c1,1.f);
  sx[nl*64+o0]   = tanhf(bf2f(Hin[n*192+o0])   + rbias[o0]   + a00*i0 + a10*i1);
  sx[nl*64+o0+1] = tanhf(bf2f(Hin[n*192+o0+1]) + rbias[o0+1] + a01*i0 + a11*i1);
  __syncthreads();
  if (t < 192){
    int c = t % 96, grp = t / 96;            // grp 0/1: nodes grp*4..+3
    float acc[4] = {0,0,0,0};
    for (int i=0;i<64;i++){
      float w = Wc[i*96 + c];
      #pragma unroll
      for (int tt=0;tt<4;tt++) acc[tt] += sx[(grp*4+tt)*64+i]*w;
    }
    #pragma unroll
    for (int tt=0;tt<4;tt++) Hout[(n0+grp*4+tt)*96 + c] = f2bf(acc[tt]);
  }
}

// ---- F4: ragg<32> (Hin stride 96) + GAT h=x@gw + scores ----
__global__ void __launch_bounds__(256) k_f4(
    const unsigned short* __restrict__ Hin, const float* __restrict__ rbias,
    const int* __restrict__ degc, const int* __restrict__ pks,
    const float* __restrict__ gw, const float* __restrict__ as_,
    const float* __restrict__ ad_,
    unsigned short* __restrict__ h16, float* __restrict__ asv, float* __restrict__ adv){
  __shared__ float sx[8*32];
  __shared__ float red[4][16];
  int n0 = blockIdx.x*8;
  int t = threadIdx.x, nl = t>>5, o = t&31, n = n0+nl;
  int r0 = n*CAP, r1 = r0 + degc[n];
  float a0=0.f, a1=0.f, c0=0.f, c1=0.f;
  for (int j=r0;j<r1;j++){
    int p = pks[j];
    if (PK_SELF(p)) continue;
    int rel = PK_REL(p);
    float v = bf2f(Hin[PK_SRC(p)*96 + 32 + rel*32 + o]);
    if (rel==0){ a0 += v; c0 += 1.f; } else { a1 += v; c1 += 1.f; }
  }
  sx[nl*32+o] = tanhf(bf2f(Hin[n*96+o]) + rbias[o]
                      + a0/fmaxf(c0,1.f) + a1/fmaxf(c1,1.f));
  __syncthreads();
  int c2 = t*2;
  float2 acc[8];
  #pragma unroll
  for (int k=0;k<8;k++) acc[k] = {0.f,0.f};
  for (int i=0;i<32;i++){
    const float2 g = *(const float2*)&gw[i*512 + c2];
    #pragma unroll
    for (int k=0;k<8;k++){
      float xv = sx[k*32+i];
      acc[k].x += xv*g.x; acc[k].y += xv*g.y;
    }
  }
  const float2 a2 = *(const float2*)&as_[c2];
  const float2 d2 = *(const float2*)&ad_[c2];
  float sa[8], sd[8];
  #pragma unroll
  for (int k=0;k<8;k++){
    ushort2 ov;
    ov.x = f2bf(acc[k].x); ov.y = f2bf(acc[k].y);
    *(ushort2*)&h16[(n0+k)*512 + c2] = ov;
    sa[k] = acc[k].x*a2.x + acc[k].y*a2.y;
    sd[k] = acc[k].x*d2.x + acc[k].y*d2.y;
  }
  #pragma unroll
  for (int m=32;m>0;m>>=1){
    #pragma unroll
    for (int k=0;k<8;k++){ sa[k] += __shfl_xor(sa[k],m,64); sd[k] += __shfl_xor(sd[k],m,64); }
  }
  int wv = t>>6;
  if ((t&63)==0){
    #pragma unroll
    for (int k=0;k<8;k++){ red[wv][k]=sa[k]; red[wv][8+k]=sd[k]; }
  }
  __syncthreads();
  if (t<8)        asv[n0+t]   = red[0][t]+red[1][t]+red[2][t]+red[3][t];
  else if (t<16)  adv[n0+t-8] = red[0][t]+red[1][t]+red[2][t]+red[3][t];
}

// fused softmax + aggregation + bias + relu: 1 wave per node (6000 blocks).
__global__ void __launch_bounds__(64) k_gsa(
    const int* __restrict__ degc, const int* __restrict__ pks,
    const float* __restrict__ asv, const float* __restrict__ adv,
    const unsigned short* __restrict__ h16, const float* __restrict__ bias,
    unsigned short* __restrict__ gout16){
  __shared__ float sex[64];
  __shared__ int  ssrc[64];
  int n = blockIdx.x;
  int lane = threadIdx.x;
  int r0 = n*CAP, r1 = r0 + degc[n];
  float advn = adv[n];
  float m = -1e30f;
  for (int j = r0 + lane; j < r1; j += 64){
    float a = asv[PK_SRC(pks[j])] + advn; a = (a>=0.f)? a : 0.2f*a;
    m = fmaxf(m, a);
  }
  #pragma unroll
  for (int off=32;off>0;off>>=1) m = fmaxf(m, __shfl_xor(m,off,64));
  float acc[8] = {0,0,0,0,0,0,0,0};
  float sumex = 0.f;
  for (int base = r0; base < r1; base += 64){
    int j = base + lane;
    float ex = 0.f; int src = 0;
    if (j < r1){
      int p = pks[j]; src = PK_SRC(p);
      float a = asv[src] + advn; a = (a>=0.f)? a : 0.2f*a;
      ex = expf(a - m);
      sumex += ex;
    }
    __syncthreads();
    sex[lane] = ex; ssrc[lane] = src;
    __syncthreads();
    int ce = min(64, r1 - base);
    for (int e = 0; e < ce; e++){
      float cf = sex[e];
      const u16x8 hv = *(const u16x8*)&h16[(size_t)ssrc[e]*512 + lane*8];
      #pragma unroll
      for (int q=0;q<8;q++) acc[q] += cf * bf2f(hv[q]);
    }
  }
  #pragma unroll
  for (int off=32;off>0;off>>=1) sumex += __shfl_xor(sumex,off,64);
  float inv = 1.f / fmaxf(sumex, 1e-16f);
  const float4 b0 = *(const float4*)&bias[lane*8];
  const float4 b1v = *(const float4*)&bias[lane*8+4];
  u16x8 o;
  o[0] = f2bf(fmaxf(acc[0]*inv + b0.x, 0.f));
  o[1] = f2bf(fmaxf(acc[1]*inv + b0.y, 0.f));
  o[2] = f2bf(fmaxf(acc[2]*inv + b0.z, 0.f));
  o[3] = f2bf(fmaxf(acc[3]*inv + b0.w, 0.f));
  o[4] = f2bf(fmaxf(acc[4]*inv + b1v.x, 0.f));
  o[5] = f2bf(fmaxf(acc[5]*inv + b1v.y, 0.f));
  o[6] = f2bf(fmaxf(acc[6]*inv + b1v.z, 0.f));
  o[7] = f2bf(fmaxf(acc[7]*inv + b1v.w, 0.f));
  *(u16x8*)&gout16[(size_t)n*512 + lane*8] = o;
}

// ---- edge MLP precompute via MFMA: P16[6000][256] = gout16 @ Bt16^T (bf16 out) ----
__global__ void __launch_bounds__(64) k_AB(const unsigned short* __restrict__ gout16,
                                           const unsigned short* __restrict__ Bt16,
                                           unsigned short* __restrict__ P16){
  int lane = threadIdx.x;
  int mt = blockIdx.x >> 2;        // 375 row tiles
  int nt = blockIdx.x & 3;         // 4 col groups of 64
  int kq = (lane >> 4) * 8;
  const unsigned short* arow = gout16 + (size_t)(mt*16 + (lane & 15))*512 + kq;
  const unsigned short* bbase = Bt16 + (size_t)(nt*64 + (lane & 15))*512 + kq;
  f32x4 acc0 = {0,0,0,0}, acc1 = {0,0,0,0}, acc2 = {0,0,0,0}, acc3 = {0,0,0,0};
  for (int k = 0; k < 512; k += 32){
    frag8 a = *(const frag8*)(arow + k);
    frag8 b0 = *(const frag8*)(bbase + k);
    frag8 b1 = *(const frag8*)(bbase + 16*512 + k);
    frag8 b2 = *(const frag8*)(bbase + 32*512 + k);
    frag8 b3 = *(const frag8*)(bbase + 48*512 + k);
    acc0 = __builtin_amdgcn_mfma_f32_16x16x32_bf16(a, b0, acc0, 0, 0, 0);
    acc1 = __builtin_amdgcn_mfma_f32_16x16x32_bf16(a, b1, acc1, 0, 0, 0);
    acc2 = __builtin_amdgcn_mfma_f32_16x16x32_bf16(a, b2, acc2, 0, 0, 0);
    acc3 = __builtin_amdgcn_mfma_f32_16x16x32_bf16(a, b3, acc3, 0, 0, 0);
  }
  int rowb = mt*16 + (lane >> 4)*4;
  int col  = nt*64 + (lane & 15);
  #pragma unroll
  for (int i=0;i<4;i++){
    P16[(size_t)(rowb+i)*256 + col     ] = f2bf(acc0[i]);
    P16[(size_t)(rowb+i)*256 + col + 16] = f2bf(acc1[i]);
    P16[(size_t)(rowb+i)*256 + col + 32] = f2bf(acc2[i]);
    P16[(size_t)(rowb+i)*256 + col + 48] = f2bf(acc3[i]);
  }
}

// per-edge MLP head: 16 lanes/edge, bf16 P loads
__global__ void k_edge(const int* __restrict__ ei, const unsigned short* __restrict__ P16,
                       const float* __restrict__ b1,
                       const float* __restrict__ w2, const float* __restrict__ b2,
                       float* __restrict__ out){
  int e = blockIdx.x*16 + (threadIdx.x >> 4);
  int l = threadIdx.x & 15;            // lane covers channels [l*8, l*8+8)
  if (e >= EE) return;
  int s = ei[e], d = ei[EE+e];
  const u16x8 Av = *(const u16x8*)&P16[(size_t)s*256 + l*8];
  const u16x8 Bv = *(const u16x8*)&P16[(size_t)d*256 + 128 + l*8];
  const float4 b1a = *(const float4*)&b1[l*8];
  const float4 b1b = *(const float4*)&b1[l*8+4];
  const float4 w2a = *(const float4*)&w2[l*8];
  const float4 w2b = *(const float4*)&w2[l*8+4];
  float h0 = fmaxf(bf2f(Av[0])+bf2f(Bv[0])+b1a.x, 0.f);
  float h1 = fmaxf(bf2f(Av[1])+bf2f(Bv[1])+b1a.y, 0.f);
  float h2 = fmaxf(bf2f(Av[2])+bf2f(Bv[2])+b1a.z, 0.f);
  float h3 = fmaxf(bf2f(Av[3])+bf2f(Bv[3])+b1a.w, 0.f);
  float h4 = fmaxf(bf2f(Av[4])+bf2f(Bv[4])+b1b.x, 0.f);
  float h5 = fmaxf(bf2f(Av[5])+bf2f(Bv[5])+b1b.y, 0.f);
  float h6 = fmaxf(bf2f(Av[6])+bf2f(Bv[6])+b1b.z, 0.f);
  float h7 = fmaxf(bf2f(Av[7])+bf2f(Bv[7])+b1b.w, 0.f);
  float acc = h0*w2a.x + h1*w2a.y + h2*w2a.z + h3*w2a.w
            + h4*w2b.x + h5*w2b.y + h6*w2b.z + h7*w2b.w;
  #pragma unroll
  for (int m=8;m>0;m>>=1) acc += __shfl_xor(acc,m,64);
  if (l==0) out[e] = 1.f/(1.f + expf(-(acc + b2[0])));
}

extern "C" void kernel_launch(void* const* d_in, const int* in_sizes, int n_in,
                              void* d_out, int out_size, void* d_ws, size_t ws_size,
                              hipStream_t stream){
  const float* basis0 = (const float*)d_in[0];
  const float* comp0  = (const float*)d_in[1];
  const float* root0  = (const float*)d_in[2];
  const float* rbias0 = (const float*)d_in[3];
  const float* basis1 = (const float*)d_in[4];
  const float* comp1  = (const float*)d_in[5];
  const float* root1  = (const float*)d_in[6];
  const float* rbias1 = (const float*)d_in[7];
  const float* basis2 = (const float*)d_in[8];
  const float* comp2  = (const float*)d_in[9];
  const float* root2  = (const float*)d_in[10];
  const float* rbias2 = (const float*)d_in[11];
  const float* basis3 = (const float*)d_in[12];
  const float* comp3  = (const float*)d_in[13];
  const float* root3  = (const float*)d_in[14];
  const float* rbias3 = (const float*)d_in[15];
  const float* gat_w = (const float*)d_in[16];
  const float* a_src = (const float*)d_in[17];
  const float* a_dst = (const float*)d_in[18];
  const float* gat_b = (const float*)d_in[19];
  const float* w1 = (const float*)d_in[20];
  const float* b1 = (const float*)d_in[21];
  const float* w2 = (const float*)d_in[22];
  const float* b2 = (const float*)d_in[23];
  const int* ei = (const int*)d_in[24];
  const int* et = (const int*)d_in[25];
  float* out = (float*)d_out;

  // workspace carve-up (16B-aligned sections)
  float* p = (float*)d_ws;
  int* cursor = (int*)p; p += NN;              // doubles as degree after k_pdc
  int* pks    = (int*)p; p += NN*CAP;          // bucket CSR (64 slots/node)
  unsigned short* W016 = (unsigned short*)p; p += NN*32;       // 2*NN*32 bf16
  float* Wcat = p; p += 24576;
  unsigned short* Bt16 = (unsigned short*)p; p += 256*512/2;
  unsigned short* H16a = (unsigned short*)p; p += NN*96;       // NN*192 bf16
  unsigned short* H16b = (unsigned short*)p; p += NN*96;       // NN*192 bf16
  unsigned short* h16  = (unsigned short*)p; p += NN*256;      // NN*512 bf16
  float* asv  = p; p += NN;
  float* adv  = p; p += NN;
  unsigned short* gout16 = (unsigned short*)p; p += NN*256;    // NN*512 bf16
  unsigned short* P16 = (unsigned short*)p; p += NN*128;       // NN*256 bf16

  auto grid = [](long long n){ return dim3((unsigned)((n + 255)/256)); };

  // ---- zero cursor only, then single fused prep kernel ----
  hipMemsetAsync(cursor, 0, (size_t)NN*sizeof(int), stream);
  k_pdc<<<grid(2LL*NN*32 + 24576 + 256*512),256,0,stream>>>(ei, et, cursor, pks,
        basis0, comp0, basis1,comp1,root1, basis2,comp2,root2,
        basis3,comp3,root3, w1, W016, Wcat, Bt16);

  // ---- RGCN stack (fused gather+mm per layer; rel-counts derived locally) ----
  k_f1<<<dim3(NN/8),256,0,stream>>>(W016, root0, rbias0, cursor, pks, Wcat, H16a);
  k_f2<<<dim3(NN/8),256,0,stream>>>(H16a, rbias1, cursor, pks, Wcat + 6144, H16b);
  k_f3<<<dim3(NN/8),256,0,stream>>>(H16b, rbias2, cursor, pks, Wcat + 18432, H16a);
  k_f4<<<dim3(NN/8),256,0,stream>>>(H16a, rbias3, cursor, pks,
                                    gat_w, a_src, a_dst, h16, asv, adv);

  // ---- GAT softmax+aggregate (1 wave/node) ----
  k_gsa<<<dim3(NN),64,0,stream>>>(cursor, pks, asv, adv, h16, gat_b, gout16);

  // ---- edge MLP: MFMA GEMM then per-edge head ----
  k_AB<<<dim3(1500),64,0,stream>>>(gout16, Bt16, P16);
  k_edge<<<dim3((EE+15)/16),256,0,stream>>>(ei, P16, b1, w2, b2, out);
}